// Round 3
// baseline (122.024 us; speedup 1.0000x reference)
//
#include <hip/hip_runtime.h>
#include <math.h>

#define CNUM 20
#define KNUM 64
#define DDIM 256
#define NHB 64

typedef __attribute__((ext_vector_type(8))) short short8;
typedef __attribute__((ext_vector_type(4))) unsigned short u16x4;
typedef __attribute__((ext_vector_type(4))) float f32x4;

static __device__ __forceinline__ float shfl_xor_f(float v, int m) {
    return __shfl_xor(v, m, 64);
}

static __device__ __forceinline__ unsigned short f2bf(float f) {
    union { float f; unsigned u; } x; x.f = f;
    unsigned r = x.u + 0x7FFF + ((x.u >> 16) & 1);   // RTN-even
    return (unsigned short)(r >> 16);
}

// ---- K0: per-(c,k) stats (mu2, 1/tau, log tau, valid), rstd, med*rstd, mu->bf16 ----
__global__ void k_prep(const float* __restrict__ mu, const float* __restrict__ exp_temp,
                       const float* __restrict__ runa, const float* __restrict__ runb,
                       const float* __restrict__ med, const float* __restrict__ stdv,
                       float* __restrict__ mu2, float* __restrict__ rtau,
                       float* __restrict__ ltau, float* __restrict__ vldf,
                       float* __restrict__ rstd, float* __restrict__ mrs,
                       unsigned short* __restrict__ mubf)
{
    const int tid = threadIdx.x, w = tid >> 6, lane = tid & 63;
    if (blockIdx.x == 0) {
        const float r = 1.0f / stdv[tid];               // blockDim==DDIM==256
        rstd[tid] = r;
        mrs[tid] = med[tid] * r;
    }
    const int ck = blockIdx.x * 4 + w;
    if (ck >= CNUM * KNUM) return;
    const float4 v = *(const float4*)(mu + (size_t)ck * DDIM + lane * 4);
    u16x4 pk;
    pk[0] = f2bf(v.x); pk[1] = f2bf(v.y); pk[2] = f2bf(v.z); pk[3] = f2bf(v.w);
    *(u16x4*)(mubf + (size_t)ck * DDIM + lane * 4) = pk;
    float s = v.x * v.x + v.y * v.y + v.z * v.z + v.w * v.w;
#pragma unroll
    for (int off = 32; off > 0; off >>= 1) s += shfl_xor_f(s, off);
    if (lane == 0) {
        mu2[ck] = s;
        const float e = exp_temp[ck];
        const float t = 100.0f / (1.0f + __expf(-0.5f * e)) + 0.01f;
        rtau[ck] = 1.0f / t;
        ltau[ck] = logf(t);
        const int c = ck >> 6;
        const float thr = runb[c] * (0.5f / (float)KNUM);
        vldf[ck] = (runa[ck] > thr) ? 1.0f : 0.0f;
    }
}

// ---- K1: per-block class histogram ----
__global__ void k_hist(const int* __restrict__ labels, int N, int* __restrict__ bc)
{
    __shared__ int h[CNUM];
    const int tid = threadIdx.x;
    if (tid < CNUM) h[tid] = 0;
    __syncthreads();
    for (int i = blockIdx.x * blockDim.x + tid; i < N; i += gridDim.x * blockDim.x)
        atomicAdd(&h[labels[i]], 1);
    __syncthreads();
    if (tid < CNUM) bc[blockIdx.x * CNUM + tid] = h[tid];
}

// ---- K2: counts, padded offsets, scatter bases, block->class map ----
__global__ void k_scan(const int* __restrict__ bc, int nb, int* __restrict__ cnt,
                       int* __restrict__ ps, int* __restrict__ sb,
                       int* __restrict__ blk2cls)
{
    const int t = threadIdx.x;
    if (t < CNUM) {
        int s = 0;
#pragma unroll 8
        for (int b = 0; b < nb; b++) s += bc[b * CNUM + t];
        cnt[t] = s;
    }
    __syncthreads();
    if (t == 0) {
        int run = 0;
        for (int c = 0; c < CNUM; c++) { ps[c] = run; run += (cnt[c] + 63) & ~63; }
        ps[CNUM] = run;
    }
    __syncthreads();
    if (t < CNUM) {
        int run = ps[t];
#pragma unroll 8
        for (int b = 0; b < nb; b++) { sb[b * CNUM + t] = run; run += bc[b * CNUM + t]; }
        const int b0 = ps[t] >> 6, b1 = ps[t + 1] >> 6;
        for (int b = b0; b < b1; b++) blk2cls[b] = t;
    }
}

// ---- K3: scatter sample ids into class-sorted padded index array ----
__global__ void k_scatter(const int* __restrict__ labels, int N, const int* __restrict__ sb,
                          int* __restrict__ idx)
{
    __shared__ int cur[CNUM];
    const int tid = threadIdx.x;
    if (tid < CNUM) cur[tid] = sb[blockIdx.x * CNUM + tid];
    __syncthreads();
    for (int i = blockIdx.x * blockDim.x + tid; i < N; i += gridDim.x * blockDim.x) {
        const int c = labels[i];
        const int p = atomicAdd(&cur[c], 1);
        idx[p] = i;
    }
}

// ---- K4: main — LDS-free, barrier-free; wave = 16 samples x all 64 k ----
__global__ __launch_bounds__(256, 4)
void k_main(const float* __restrict__ data, const unsigned short* __restrict__ mubf,
            const float* __restrict__ mrs, const float* __restrict__ rstd,
            const float* __restrict__ mu2, const float* __restrict__ rtau,
            const float* __restrict__ ltau, const float* __restrict__ vldf,
            const int* __restrict__ idx, const int* __restrict__ ps,
            const int* __restrict__ blk2cls, float* __restrict__ wpart)
{
    const int tid = threadIdx.x, w = tid >> 6, lane = tid & 63;
    const int g = blockIdx.x;
    const int slot0 = g * 64;
    const int padtot = ps[CNUM];
    if (slot0 >= padtot) { if (lane == 0) wpart[g * 4 + w] = 0.f; return; }
    const int c = blk2cls[g];
    const int n16 = lane & 15, kg = lane >> 4;

    const int n = idx[slot0 + 16 * w + n16];
    const float act = (n >= 0) ? 1.0f : 0.0f;
    const int nn = (n >= 0) ? n : 0;
    const float* __restrict__ xrow = data + (size_t)nn * DDIM;

    // load + normalize this lane's quarter of the sample row -> 8 bf16x8 B-frags
    short8 xb[8];
    float q = 0.f;
#pragma unroll
    for (int s = 0; s < 8; ++s) {
        const int d = 32 * s + 8 * kg;
        const float4 u0 = *(const float4*)(xrow + d);
        const float4 u1 = *(const float4*)(xrow + d + 4);
        const float4 r0 = *(const float4*)(rstd + d);
        const float4 r1 = *(const float4*)(rstd + d + 4);
        const float4 m0 = *(const float4*)(mrs + d);
        const float4 m1 = *(const float4*)(mrs + d + 4);
        float a[8];
        a[0] = act * fmaf(u0.x, r0.x, -m0.x); a[1] = act * fmaf(u0.y, r0.y, -m0.y);
        a[2] = act * fmaf(u0.z, r0.z, -m0.z); a[3] = act * fmaf(u0.w, r0.w, -m0.w);
        a[4] = act * fmaf(u1.x, r1.x, -m1.x); a[5] = act * fmaf(u1.y, r1.y, -m1.y);
        a[6] = act * fmaf(u1.z, r1.z, -m1.z); a[7] = act * fmaf(u1.w, r1.w, -m1.w);
        short8 pk;
#pragma unroll
        for (int j = 0; j < 8; ++j) {
            q = fmaf(a[j], a[j], q);
            pk[j] = (short)f2bf(a[j]);
        }
        xb[s] = pk;
    }
    // full |x|^2 for this lane's sample (combine 4 kg quarters)
    q += shfl_xor_f(q, 16);
    q += shfl_xor_f(q, 32);

    // MFMA: A = mu rows (k), B = x rows (samples); C[k][sample]
    f32x4 acc[4] = {};
    const unsigned short* __restrict__ mbase = mubf + (size_t)c * KNUM * DDIM;
#pragma unroll
    for (int s = 0; s < 8; ++s) {
        short8 af[4];
#pragma unroll
        for (int f = 0; f < 4; ++f)
            af[f] = *(const short8*)(mbase + (16 * f + n16) * DDIM + 32 * s + 8 * kg);
#pragma unroll
        for (int f = 0; f < 4; ++f)
            acc[f] = __builtin_amdgcn_mfma_f32_16x16x32_bf16(af[f], xb[s], acc[f], 0, 0, 0);
    }

    // epilogue: lane holds 16 k-values (k = 16f + 4kg + r) of its sample
    const int ckb = c * KNUM;
    float simv[16], lpv[16];
    float mxv = -3.4e38f;
#pragma unroll
    for (int f = 0; f < 4; ++f) {
        const int kb = ckb + 16 * f + 4 * kg;
        const float4 m2v = *(const float4*)(mu2 + kb);
        const float4 rtv = *(const float4*)(rtau + kb);
        const float4 ltv = *(const float4*)(ltau + kb);
        const float4 vlv = *(const float4*)(vldf + kb);
#pragma unroll
        for (int r = 0; r < 4; ++r) {
            const float m2 = (&m2v.x)[r];
            const float d2 = fmaxf(fmaf(-2.0f, acc[f][r], q + m2), 0.f);
            const float dist = -6.25f * sqrtf(d2);          // 100/sqrt(256)
            const float sim = ((&vlv.x)[r] > 0.5f) ? dist : -1.0e12f;
            simv[4 * f + r] = sim;
            lpv[4 * f + r] = fmaf(sim, (&rtv.x)[r], -(&ltv.x)[r]);
            mxv = fmaxf(mxv, 0.5f * sim);
        }
    }
    mxv = fmaxf(mxv, shfl_xor_f(mxv, 16));
    mxv = fmaxf(mxv, shfl_xor_f(mxv, 32));
    float se = 0.f, sl = 0.f;
#pragma unroll
    for (int i = 0; i < 16; ++i) {
        const float e = __expf(fmaf(0.5f, simv[i], -mxv));
        se += e;
        sl = fmaf(e, lpv[i], sl);
    }
    se += shfl_xor_f(se, 16); se += shfl_xor_f(se, 32);
    sl += shfl_xor_f(sl, 16); sl += shfl_xor_f(sl, 32);
    float res = (kg == 0 && n >= 0) ? (-sl / se) : 0.f;
    res += shfl_xor_f(res, 1);
    res += shfl_xor_f(res, 2);
    res += shfl_xor_f(res, 4);
    res += shfl_xor_f(res, 8);
    if (lane == 0) wpart[g * 4 + w] = res;
}

// ---- K5: deterministic per-class reduce -> loss ----
__global__ void k_final(const float* __restrict__ wpart, const int* __restrict__ ps,
                        const int* __restrict__ cnt, float* __restrict__ out)
{
    __shared__ float seg[CNUM];
    const int t = threadIdx.x;
    if (t < CNUM) {
        float s = 0.f;
        const int b0 = ps[t] >> 6, b1 = ps[t + 1] >> 6;
        for (int b = b0; b < b1; b++) {
            const float4 v = *(const float4*)(wpart + 4 * b);
            s += ((v.x + v.y) + (v.z + v.w));
        }
        seg[t] = s;
    }
    __syncthreads();
    if (t == 0) {
        float loss = 0.f;
        for (int c = 0; c < CNUM; c++) {
            const float cc = (float)cnt[c];
            if (cc > 0.f) loss += seg[c] / fmaxf(cc, 1.0f);
        }
        out[0] = loss;
    }
}

extern "C" void kernel_launch(void* const* d_in, const int* in_sizes, int n_in,
                              void* d_out, int out_size, void* d_ws, size_t ws_size,
                              hipStream_t stream)
{
    const float* data     = (const float*)d_in[0];
    const int*   labels   = (const int*)d_in[1];
    const float* mu       = (const float*)d_in[2];
    const float* exp_temp = (const float*)d_in[3];
    const float* med      = (const float*)d_in[4];
    const float* stdv     = (const float*)d_in[5];
    const float* runa     = (const float*)d_in[6];
    const float* runb     = (const float*)d_in[7];
    float* out = (float*)d_out;
    const int N = in_sizes[0] / DDIM;

    char* w = (char*)d_ws;
    float* mu2  = (float*)w; w += (size_t)CNUM * KNUM * 4;
    float* rtau = (float*)w; w += (size_t)CNUM * KNUM * 4;
    float* ltau = (float*)w; w += (size_t)CNUM * KNUM * 4;
    float* vldf = (float*)w; w += (size_t)CNUM * KNUM * 4;
    float* rstd = (float*)w; w += (size_t)DDIM * 4;
    float* mrs  = (float*)w; w += (size_t)DDIM * 4;
    unsigned short* mubf = (unsigned short*)w; w += (size_t)CNUM * KNUM * DDIM * 2;
    int* bc  = (int*)w; w += (size_t)NHB * CNUM * 4;
    int* sb  = (int*)w; w += (size_t)NHB * CNUM * 4;
    int* cnt = (int*)w; w += 64 * 4;
    int* ps  = (int*)w; w += 64 * 4;
    const int idx_slots = N + CNUM * 64;
    int* idx = (int*)w; w += (size_t)idx_slots * 4;
    const int NB = (idx_slots + 63) / 64;
    int* blk2cls = (int*)w; w += (size_t)NB * 4;
    float* wp = (float*)w; w += (size_t)NB * 4 * 4;

    k_prep<<<dim3((CNUM * KNUM + 3) / 4), dim3(256), 0, stream>>>(
        mu, exp_temp, runa, runb, med, stdv, mu2, rtau, ltau, vldf, rstd, mrs, mubf);
    k_hist<<<dim3(NHB), dim3(256), 0, stream>>>(labels, N, bc);
    k_scan<<<dim3(1), dim3(64), 0, stream>>>(bc, NHB, cnt, ps, sb, blk2cls);
    hipMemsetAsync(idx, 0xFF, (size_t)idx_slots * 4, stream);   // idx = -1 (padding)
    k_scatter<<<dim3(NHB), dim3(256), 0, stream>>>(labels, N, sb, idx);
    k_main<<<dim3(NB), dim3(256), 0, stream>>>(
        data, mubf, mrs, rstd, mu2, rtau, ltau, vldf, idx, ps, blk2cls, wp);
    k_final<<<dim3(1), dim3(32), 0, stream>>>(wp, ps, cnt, out);
}